// Round 1
// baseline (4997.179 us; speedup 1.0000x reference)
//
#include <hip/hip_runtime.h>

#define BB 64
#define TT 4096
#define HH 256
#define NTOK (BB * TT)
#define ZS 290  // z row stride in f16 elems: 580B -> bank stride 145 % 32 = 17, coprime -> conflict-free

typedef _Float16 f16;
typedef _Float16 f16x2 __attribute__((ext_vector_type(2)));

__device__ __forceinline__ f16x2 u2h(unsigned int u) {
    return __builtin_bit_cast(f16x2, u);
}

__device__ __forceinline__ float fdot2(f16x2 a, f16x2 b, float c) {
#if __has_builtin(__builtin_amdgcn_fdot2)
    return __builtin_amdgcn_fdot2(a, b, c, false);
#else
    return c + (float)a[0] * (float)b[0] + (float)a[1] * (float)b[1];
#endif
}

// ---------------- prep: fp32 -> f16 with zero-padded K dimension ----------------
__global__ __launch_bounds__(256) void cvt_pad_kernel(const float* __restrict__ src,
                                                      f16* __restrict__ dst,
                                                      int N, int K, int KP) {
    int i = blockIdx.x * 256 + threadIdx.x;
    if (i >= N * KP) return;
    int n = i / KP, k = i - n * KP;
    dst[i] = (f16)((k < K) ? src[n * K + k] : 0.0f);
}

// ---------------- RNN: 64 blocks (one per batch), 256 threads (one per h elem) ----------------
// W_hh row j lives in 128 VGPRs (f16x2). h double-buffered in LDS (f16), broadcast reads.
__global__ __launch_bounds__(256) void rnn_kernel(const float* __restrict__ x,
                                                  const float* __restrict__ Wih,
                                                  const float* __restrict__ bih,
                                                  const float* __restrict__ bhh,
                                                  const f16* __restrict__ w16,
                                                  f16* __restrict__ ht,
                                                  float* __restrict__ hlast) {
    const int b = blockIdx.x;
    const int j = threadIdx.x;
    __shared__ uint4 hb4[2][HH / 8];  // 2 x 256 f16

    // preload W_hh row j into registers (one-time)
    uint4 wv[32];
    const uint4* wrow = (const uint4*)(w16 + (size_t)j * HH);
#pragma unroll
    for (int i = 0; i < 32; ++i) wv[i] = wrow[i];

    float wih[7];
#pragma unroll
    for (int i = 0; i < 7; ++i) wih[i] = Wih[j * 7 + i];
    const float bias = bih[j] + bhh[j];

    if (j < HH / 8) hb4[0][j] = make_uint4(0u, 0u, 0u, 0u);  // h0 = 0

    const float4* xr = (const float4*)(x + (size_t)b * TT * 12);
    float4 xa = xr[0];
    float4 xb = xr[1];
    f16* htp = ht + (size_t)b * TT * HH + j;

    __syncthreads();
    int cur = 0;
    for (int t = 0; t < TT; ++t) {
        // prefetch next step's x row (uniform -> scalar loads)
        int tn = (t + 1 < TT) ? (t + 1) : t;
        float4 nxa = xr[tn * 3];
        float4 nxb = xr[tn * 3 + 1];

        // xW contribution (7 input features) + bias
        float a0 = fmaf(xa.x, wih[0], bias);
        a0 = fmaf(xa.y, wih[1], a0);
        a0 = fmaf(xa.z, wih[2], a0);
        a0 = fmaf(xa.w, wih[3], a0);
        float a1 = xb.x * wih[4];
        a1 = fmaf(xb.y, wih[5], a1);
        a1 = fmaf(xb.z, wih[6], a1);
        float a2 = 0.0f, a3 = 0.0f;

        // h @ W_hh.T : 32 broadcast ds_read_b128 + 128 fdot2, 4 independent chains
        const uint4* hv = (const uint4*)hb4[cur];
#pragma unroll
        for (int c = 0; c < 32; ++c) {
            uint4 h8 = hv[c];
            a0 = fdot2(u2h(h8.x), u2h(wv[c].x), a0);
            a1 = fdot2(u2h(h8.y), u2h(wv[c].y), a1);
            a2 = fdot2(u2h(h8.z), u2h(wv[c].z), a2);
            a3 = fdot2(u2h(h8.w), u2h(wv[c].w), a3);
        }
        float pre = (a0 + a2) + (a1 + a3);

        // fast tanh: tanh(|x|) = (1-e^-2|x|)/(1+e^-2|x|), sign restored
        float ax = fabsf(pre);
        float e = __expf(-2.0f * ax);
        float th = __fdividef(1.0f - e, 1.0f + e);
        float h = copysignf(th, pre);

        f16 hh = (f16)h;
        htp[(size_t)t * HH] = hh;                 // coalesced 2B/lane store
        ((f16*)hb4[cur ^ 1])[j] = hh;             // write to other buffer
        if (t == TT - 1) hlast[b * HH + j] = h;   // fp32 final state
        __syncthreads();                          // single barrier per step
        cur ^= 1;
        xa = nxa; xb = nxb;
    }
}

// ---------------- MLP: 64 tokens/block, K split over 4 waves, z chunk in registers ----------------
struct MlpW {
    const f16* w[7];
    const float* b[7];
};

template <int KP, int N, bool LAST>
__device__ __forceinline__ void mlp_layer(const f16* __restrict__ wgl,
                                          const float* __restrict__ bias,
                                          f16* z, float* part,
                                          int l, int w, int tok0,
                                          float* __restrict__ out) {
    constexpr int CK = KP / 4;   // k-chunk per wave
    constexpr int C2 = CK / 2;   // half2 count per chunk
    constexpr int NB = (N < 16) ? N : 16;

    // load this thread's z chunk into registers (conflict-free: stride 17l mod 32)
    f16x2 zc[C2];
#pragma unroll
    for (int i = 0; i < C2; ++i)
        zc[i] = *(const f16x2*)&z[l * ZS + w * CK + 2 * i];

    const unsigned int* wq = (const unsigned int*)wgl;  // half2 units, row stride KP/2
    for (int n0 = 0; n0 < N; n0 += NB) {
        float acc[NB];
#pragma unroll
        for (int nn = 0; nn < NB; ++nn) acc[nn] = 0.0f;
        // i-outer / nn-inner: NB independent dependency chains; weight loads wave-uniform -> scalar
#pragma unroll
        for (int i = 0; i < C2; ++i) {
#pragma unroll
            for (int nn = 0; nn < NB; ++nn) {
                unsigned int wb = wq[(n0 + nn) * (KP / 2) + w * C2 + i];
                acc[nn] = fdot2(zc[i], u2h(wb), acc[nn]);
            }
        }
        __syncthreads();  // previous batch's reduce done before part overwrite
#pragma unroll
        for (int nn = 0; nn < NB; ++nn)
            part[(nn * 4 + w) * 64 + l] = acc[nn];  // lanes consecutive -> conflict-free
        __syncthreads();
        const int tid = threadIdx.x;
        for (int idx = tid; idx < NB * 64; idx += 256) {
            int nn = idx >> 6, ll = idx & 63;
            int n = n0 + nn;
            float s = part[(nn * 4 + 0) * 64 + ll] + part[(nn * 4 + 1) * 64 + ll] +
                      part[(nn * 4 + 2) * 64 + ll] + part[(nn * 4 + 3) * 64 + ll];
            s += bias[n];
            if (LAST) {
                out[(size_t)(tok0 + ll) * 7 + n] = s;
            } else {
                s = (s > 0.0f) ? s : 0.01f * s;   // leaky_relu(0.01)
                z[ll * ZS + n] = (f16)s;
            }
        }
    }
    __syncthreads();  // z writes visible before next layer's chunk loads
}

__global__ __launch_bounds__(256) void mlp_kernel(const f16* __restrict__ ht,
                                                  const float* __restrict__ x,
                                                  MlpW mw,
                                                  float* __restrict__ out) {
    __shared__ f16 z[64 * ZS];          // 37120 B
    __shared__ float part[16 * 4 * 64]; // 16384 B
    const int tid = threadIdx.x;
    const int tok0 = blockIdx.x * 64;

    // stage ht rows (coalesced b32)
    const unsigned int* htu = (const unsigned int*)ht;
#pragma unroll
    for (int it = 0; it < 32; ++it) {
        int idx = it * 256 + tid;
        int r = idx >> 7, c2 = idx & 127;
        unsigned int v = htu[(size_t)(tok0 + r) * 128 + c2];
        *(unsigned int*)&z[r * ZS + 2 * c2] = v;
    }
    // x_fixed (cols 256..260)
    if (tid < 64) {
        const float* xp = x + (size_t)(tok0 + tid) * 12 + 7;
#pragma unroll
        for (int i = 0; i < 5; ++i) z[tid * ZS + 256 + i] = (f16)xp[i];
    }
    // zero pad cols 261..287 (layer0 reads to col 287)
    for (int idx = tid; idx < 64 * 32; idx += 256) {
        int r = idx >> 5, c = 261 + (idx & 31);
        if (c < 288) z[r * ZS + c] = (f16)0.0f;
    }
    __syncthreads();

    const int l = tid & 63;
    const int w = __builtin_amdgcn_readfirstlane(tid >> 6);

    mlp_layer<288, 256, false>(mw.w[0], mw.b[0], z, part, l, w, tok0, out);
    mlp_layer<256, 128, false>(mw.w[1], mw.b[1], z, part, l, w, tok0, out);
    mlp_layer<128,  64, false>(mw.w[2], mw.b[2], z, part, l, w, tok0, out);
    mlp_layer< 64,  32, false>(mw.w[3], mw.b[3], z, part, l, w, tok0, out);
    mlp_layer< 32,  16, false>(mw.w[4], mw.b[4], z, part, l, w, tok0, out);
    mlp_layer< 16,   8, false>(mw.w[5], mw.b[5], z, part, l, w, tok0, out);
    mlp_layer<  8,   7, true >(mw.w[6], mw.b[6], z, part, l, w, tok0, out);
}

// ---------------- launch ----------------
extern "C" void kernel_launch(void* const* d_in, const int* in_sizes, int n_in,
                              void* d_out, int out_size, void* d_ws, size_t ws_size,
                              hipStream_t stream) {
    const float* x   = (const float*)d_in[0];
    const float* Wih = (const float*)d_in[1];
    const float* Whh = (const float*)d_in[2];
    const float* bih = (const float*)d_in[3];
    const float* bhh = (const float*)d_in[4];
    const float* W[7];
    const float* bb[7];
    for (int j = 0; j < 7; ++j) {
        W[j]  = (const float*)d_in[5 + 2 * j];
        bb[j] = (const float*)d_in[6 + 2 * j];
    }
    float* out = (float*)d_out;

    static const int Kd[7]  = {261, 256, 128, 64, 32, 16, 8};
    static const int KPd[7] = {288, 256, 128, 64, 32, 16, 8};
    static const int Nd[7]  = {256, 128,  64, 32, 16,  8, 7};

    // workspace layout
    char* ws = (char*)d_ws;
    f16* ht = (f16*)ws;                                  // 64*4096*256 f16 = 128 MiB
    size_t off = (size_t)NTOK * HH * 2;
    f16* w16 = (f16*)(ws + off); off += (size_t)HH * HH * 2;
    f16* wp[7];
    for (int j = 0; j < 7; ++j) {
        wp[j] = (f16*)(ws + off);
        off += (size_t)Nd[j] * KPd[j] * 2;
        off = (off + 15) & ~(size_t)15;
    }

    // prep: convert weights to f16 (re-run every call; ws is re-poisoned)
    cvt_pad_kernel<<<(HH * HH + 255) / 256, 256, 0, stream>>>(Whh, w16, HH, HH, HH);
    for (int j = 0; j < 7; ++j)
        cvt_pad_kernel<<<(Nd[j] * KPd[j] + 255) / 256, 256, 0, stream>>>(W[j], wp[j], Nd[j], Kd[j], KPd[j]);

    // RNN (writes ht f16 to ws, h_last fp32 to d_out tail)
    rnn_kernel<<<BB, 256, 0, stream>>>(x, Wih, bih, bhh, w16, ht, out + (size_t)NTOK * 7);

    // MLP head (writes ot fp32 to d_out head)
    MlpW mw;
    for (int j = 0; j < 7; ++j) { mw.w[j] = wp[j]; mw.b[j] = bb[j]; }
    mlp_kernel<<<NTOK / 64, 256, 0, stream>>>(ht, x, mw, out);
}

// Round 2
// 3502.350 us; speedup vs baseline: 1.4268x; 1.4268x over previous
//
#include <hip/hip_runtime.h>

#define BB 64
#define TT 4096
#define HH 256
#define NTOK (BB * TT)

typedef _Float16 f16;
typedef _Float16 f16x2 __attribute__((ext_vector_type(2)));
typedef unsigned int uint;
typedef unsigned short ushort;

__device__ __forceinline__ f16x2 u2h(uint u) { return __builtin_bit_cast(f16x2, u); }

__device__ __forceinline__ float fdot2(f16x2 a, f16x2 b, float c) {
#if __has_builtin(__builtin_amdgcn_fdot2)
    return __builtin_amdgcn_fdot2(a, b, c, false);
#else
    return c + (float)a[0] * (float)b[0] + (float)a[1] * (float)b[1];
#endif
}

// DPP quad_perm shuffles (VALU-only, no LDS): return partner's value
__device__ __forceinline__ float dpp_xor1(float v) {  // quad_perm [1,0,3,2] = 0xB1
    int t = __builtin_amdgcn_update_dpp(0, __builtin_bit_cast(int, v), 0xB1, 0xF, 0xF, true);
    return __builtin_bit_cast(float, t);
}
__device__ __forceinline__ float dpp_xor2(float v) {  // quad_perm [2,3,0,1] = 0x4E
    int t = __builtin_amdgcn_update_dpp(0, __builtin_bit_cast(int, v), 0x4E, 0xF, 0xF, true);
    return __builtin_bit_cast(float, t);
}
__device__ __forceinline__ float swz_xor4(float v) {  // ds_swizzle BitMode xor=4
    int t = __builtin_amdgcn_ds_swizzle(__builtin_bit_cast(int, v), 0x101F);
    return __builtin_bit_cast(float, t);
}

// ============ prep: swizzle W_hh into per-thread-contiguous f16 blocks ============
// Thread tid of rnn_kernel: j8 = tid>>3 (row group), s = tid&7 (K-octant).
// Block = rows j8*8+r (r<8), cols s*32..s*32+31, laid out [r][i] as uint4 (8 f16).
__global__ __launch_bounds__(256) void rnn_wswz_kernel(const float* __restrict__ Whh,
                                                       uint4* __restrict__ Wsw) {
    int gid = blockIdx.x * 256 + threadIdx.x;  // 8192 uint4s
    if (gid >= 256 * 32) return;
    int tid = gid >> 5, q = gid & 31;
    int r = q >> 2, i = q & 3;
    int j8 = tid >> 3, s = tid & 7;
    int row = j8 * 8 + r, col = s * 32 + i * 8;
    const float* src = Whh + row * 256 + col;
    f16 v[8];
#pragma unroll
    for (int e = 0; e < 8; ++e) v[e] = (f16)src[e];
    Wsw[gid] = *(const uint4*)v;
}

// ============ prep: MLP weights fp32[N][K] -> f16[N][KR] zero-padded ============
__global__ __launch_bounds__(256) void mlp_wpad_kernel(const float* __restrict__ W,
                                                       f16* __restrict__ dst,
                                                       int N, int K, int KR) {
    int gid = blockIdx.x * 256 + threadIdx.x;
    if (gid >= N * KR) return;
    int n = gid / KR, k = gid - n * KR;
    dst[gid] = (f16)((k < K) ? W[n * K + k] : 0.0f);
}

// ============ RNN: 64 blocks x 256 threads ============
// R=8 rows/thread, S=8-way K-split. W block in 128 VGPRs (asm-pinned).
// Per step: 4x ds_read_b128 h-octant (16 KB/CU total), 128 fdot2, butterfly
// reduce (xor4 swizzle + xor2/xor1 DPP) -> lane s holds row j8*8+s == tid.
// Barrier = lgkmcnt-only (no vmcnt drain). ht buffered 16 steps in regs.
__global__ __launch_bounds__(256, 1) void rnn_kernel(const float* __restrict__ x,
                                                     const uint4* __restrict__ Wsw,
                                                     const float* __restrict__ Wih,
                                                     const float* __restrict__ bih,
                                                     const float* __restrict__ bhh,
                                                     f16* __restrict__ ht,
                                                     float* __restrict__ hlast) {
    const int b = blockIdx.x, tid = threadIdx.x;
    const int s = tid & 7;
    __shared__ uint4 hb[2][32];    // h double buffer (256 f16 each)
    __shared__ uint4 xs[2][128];   // x tile double buffer (64 rows x 8 f32)

    // W block -> registers, pinned
    uint4 wv[32];
    const uint4* wp = Wsw + tid * 32;
#pragma unroll
    for (int i = 0; i < 32; ++i) wv[i] = wp[i];
#pragma unroll
    for (int i = 0; i < 32; ++i)
        asm volatile("" : "+v"(wv[i].x), "+v"(wv[i].y), "+v"(wv[i].z), "+v"(wv[i].w));

    float wih[7];
#pragma unroll
    for (int i = 0; i < 7; ++i) wih[i] = Wih[tid * 7 + i];
    const float bias = bih[tid] + bhh[tid];

    const float* xb = x + (size_t)b * TT * 12;
    uint4 xpre = make_uint4(0, 0, 0, 0);
    if (tid < 128) {  // waves 0,1 stage x
        int row = tid >> 1, u = tid & 1;
        xs[0][row * 2 + u] = *(const uint4*)(xb + row * 12 + u * 4);
        xpre = *(const uint4*)(xb + (64 + row) * 12 + u * 4);
    }
    if (tid < 32) hb[0][tid] = make_uint4(0, 0, 0, 0);  // h0 = 0
    __syncthreads();

    ushort hst[16];
    float hfin = 0.f;
    for (int tb = 0; tb < TT / 16; ++tb) {
#pragma unroll
        for (int k = 0; k < 16; ++k) {
            const int t = tb * 16 + k;
            const int cur = k & 1;            // == t&1
            const int tile = (t >> 6) & 1, tstep = t & 63;

            // x contribution (uniform row, broadcast from LDS) - off critical path
            const float4 xa = ((const float4*)xs[tile])[tstep * 2];
            const float4 xc = ((const float4*)xs[tile])[tstep * 2 + 1];
            float xw = fmaf(xa.x, wih[0], bias);
            xw = fmaf(xa.y, wih[1], xw);
            xw = fmaf(xa.z, wih[2], xw);
            xw = fmaf(xa.w, wih[3], xw);
            xw = fmaf(xc.x, wih[4], xw);
            xw = fmaf(xc.y, wih[5], xw);
            xw = fmaf(xc.z, wih[6], xw);

            // h octant (32 f16) for this thread's K-split
            uint4 h0 = hb[cur][s * 4 + 0];
            uint4 h1 = hb[cur][s * 4 + 1];
            uint4 h2 = hb[cur][s * 4 + 2];
            uint4 h3 = hb[cur][s * 4 + 3];

            float acc[8];
#pragma unroll
            for (int r = 0; r < 8; ++r) {
                float a = 0.f;
                a = fdot2(u2h(h0.x), u2h(wv[r * 4 + 0].x), a);
                a = fdot2(u2h(h0.y), u2h(wv[r * 4 + 0].y), a);
                a = fdot2(u2h(h0.z), u2h(wv[r * 4 + 0].z), a);
                a = fdot2(u2h(h0.w), u2h(wv[r * 4 + 0].w), a);
                a = fdot2(u2h(h1.x), u2h(wv[r * 4 + 1].x), a);
                a = fdot2(u2h(h1.y), u2h(wv[r * 4 + 1].y), a);
                a = fdot2(u2h(h1.z), u2h(wv[r * 4 + 1].z), a);
                a = fdot2(u2h(h1.w), u2h(wv[r * 4 + 1].w), a);
                a = fdot2(u2h(h2.x), u2h(wv[r * 4 + 2].x), a);
                a = fdot2(u2h(h2.y), u2h(wv[r * 4 + 2].y), a);
                a = fdot2(u2h(h2.z), u2h(wv[r * 4 + 2].z), a);
                a = fdot2(u2h(h2.w), u2h(wv[r * 4 + 2].w), a);
                a = fdot2(u2h(h3.x), u2h(wv[r * 4 + 3].x), a);
                a = fdot2(u2h(h3.y), u2h(wv[r * 4 + 3].y), a);
                a = fdot2(u2h(h3.z), u2h(wv[r * 4 + 3].z), a);
                a = fdot2(u2h(h3.w), u2h(wv[r * 4 + 3].w), a);
                acc[r] = a;
            }

            // selective butterfly: after 3 stages lane s holds row index s
#pragma unroll
            for (int i = 0; i < 4; ++i) {
                float mine = (s & 4) ? acc[i + 4] : acc[i];
                float oth = (s & 4) ? acc[i] : acc[i + 4];
                acc[i] = mine + swz_xor4(oth);
            }
#pragma unroll
            for (int i = 0; i < 2; ++i) {
                float mine = (s & 2) ? acc[i + 2] : acc[i];
                float oth = (s & 2) ? acc[i] : acc[i + 2];
                acc[i] = mine + dpp_xor2(oth);
            }
            float mine = (s & 1) ? acc[1] : acc[0];
            float oth = (s & 1) ? acc[0] : acc[1];
            float pre = mine + dpp_xor1(oth) + xw;

            // tanh via exp2-based fast path
            float ax = fabsf(pre);
            float e = __expf(-2.0f * ax);
            float th = __fdividef(1.0f - e, 1.0f + e);
            float h = copysignf(th, pre);

            if (t == TT - 1) hfin = h;
            f16 hf = (f16)h;
            ((f16*)hb[cur ^ 1])[tid] = hf;  // ds_write_b16
            hst[k] = __builtin_bit_cast(ushort, hf);

            // x tile machinery: mid-tile, commit prefetched tile+1, start tile+2
            if (tstep == 32 && tid < 128) {
                int row = tid >> 1, u = tid & 1;
                xs[tile ^ 1][row * 2 + u] = xpre;
                int nt = (t & ~63) + 128 + row;
                if (nt > TT - 1) nt = TT - 1;
                xpre = *(const uint4*)(xb + nt * 12 + u * 4);
            }
            // barrier WITHOUT vmcnt drain (ht stores stay in flight)
            asm volatile("s_waitcnt lgkmcnt(0)\n\ts_barrier" ::: "memory");
        }
        // flush 16 buffered h values (coalesced 2B/lane rows)
        size_t base = (size_t)b * TT * HH + (size_t)(tb * 16) * HH + tid;
#pragma unroll
        for (int k = 0; k < 16; ++k)
            ht[base + (size_t)k * HH] = __builtin_bit_cast(f16, hst[k]);
    }
    hlast[b * HH + tid] = hfin;
}

// ============ MLP: 1024 blocks x 256 threads, 256 tokens/block ============
// lane = tokl*4 + s: 4 tokens/thread, 4-way K-split (quad). Activations live in
// registers across ALL layers; weights staged to LDS in 64-row chunks and read
// as wave-broadcast b128; per-output DPP-quad butterfly reduce.
struct MlpP {
    const f16* w[7];
    const float* b[7];
};

template <int KR, int N, bool LAST>
__device__ __forceinline__ void mlp_layer(const f16* __restrict__ wg,
                                          const float* __restrict__ bg,
                                          f16* wl, float* bl,
                                          uint zr[4][36], uint zn[4][32],
                                          int tid, int s, size_t tok0,
                                          float* __restrict__ out) {
    constexpr int P = KR / 8;  // f16x2 pairs per K-quarter
    constexpr int CN = (N < 64) ? N : 64;
    const uint4* wg4 = (const uint4*)wg;
    for (int n0 = 0; n0 < N; n0 += CN) {
        // stage CN rows + bias chunk
        const int cnt4 = CN * KR / 8;
        const int base4 = n0 * (KR / 8);
        for (int idx = tid; idx < cnt4; idx += 256)
            ((uint4*)wl)[idx] = wg4[base4 + idx];
        if (tid < CN) bl[tid] = bg[n0 + tid];
        __syncthreads();

        for (int nn = 0; nn < CN; ++nn) {
            const f16* wrow = wl + nn * KR + s * (KR / 4);
            float a0 = 0.f, a1 = 0.f, a2 = 0.f, a3 = 0.f;
            if constexpr (P >= 4) {
                const uint4* w4 = (const uint4*)wrow;
#pragma unroll
                for (int p4 = 0; p4 < P / 4; ++p4) {
                    uint4 wb = w4[p4];
                    a0 = fdot2(u2h(zr[0][p4 * 4 + 0]), u2h(wb.x), a0);
                    a0 = fdot2(u2h(zr[0][p4 * 4 + 1]), u2h(wb.y), a0);
                    a0 = fdot2(u2h(zr[0][p4 * 4 + 2]), u2h(wb.z), a0);
                    a0 = fdot2(u2h(zr[0][p4 * 4 + 3]), u2h(wb.w), a0);
                    a1 = fdot2(u2h(zr[1][p4 * 4 + 0]), u2h(wb.x), a1);
                    a1 = fdot2(u2h(zr[1][p4 * 4 + 1]), u2h(wb.y), a1);
                    a1 = fdot2(u2h(zr[1][p4 * 4 + 2]), u2h(wb.z), a1);
                    a1 = fdot2(u2h(zr[1][p4 * 4 + 3]), u2h(wb.w), a1);
                    a2 = fdot2(u2h(zr[2][p4 * 4 + 0]), u2h(wb.x), a2);
                    a2 = fdot2(u2h(zr[2][p4 * 4 + 1]), u2h(wb.y), a2);
                    a2 = fdot2(u2h(zr[2][p4 * 4 + 2]), u2h(wb.z), a2);
                    a2 = fdot2(u2h(zr[2][p4 * 4 + 3]), u2h(wb.w), a2);
                    a3 = fdot2(u2h(zr[3][p4 * 4 + 0]), u2h(wb.x), a3);
                    a3 = fdot2(u2h(zr[3][p4 * 4 + 1]), u2h(wb.y), a3);
                    a3 = fdot2(u2h(zr[3][p4 * 4 + 2]), u2h(wb.z), a3);
                    a3 = fdot2(u2h(zr[3][p4 * 4 + 3]), u2h(wb.w), a3);
                }
            } else {
                const uint* w1 = (const uint*)wrow;
#pragma unroll
                for (int p = 0; p < P; ++p) {
                    uint wb = w1[p];
                    a0 = fdot2(u2h(zr[0][p]), u2h(wb), a0);
                    a1 = fdot2(u2h(zr[1][p]), u2h(wb), a1);
                    a2 = fdot2(u2h(zr[2][p]), u2h(wb), a2);
                    a3 = fdot2(u2h(zr[3][p]), u2h(wb), a3);
                }
            }
            const int n = n0 + nn;
            const float bn = bl[nn];
            float av[4] = {a0, a1, a2, a3};
#pragma unroll
            for (int u = 0; u < 4; ++u) {
                float v = av[u];
                v += dpp_xor1(v);
                v += dpp_xor2(v);  // full quad sum on all lanes
                v += bn;
                if constexpr (LAST) {
                    if ((n >> 1) == s) out[(tok0 + u) * 7 + n] = v;
                } else {
                    v = (v > 0.f) ? v : 0.01f * v;
                    constexpr int NQ = N / 4;
                    if (n / NQ == s) {
                        int idx = n & (NQ - 1);
                        ushort hv = __builtin_bit_cast(ushort, (f16)v);
                        if (idx & 1)
                            zn[u][idx >> 1] |= ((uint)hv) << 16;
                        else
                            zn[u][idx >> 1] = hv;
                    }
                }
            }
        }
        __syncthreads();
    }
    if constexpr (!LAST) {
#pragma unroll
        for (int u = 0; u < 4; ++u)
#pragma unroll
            for (int i = 0; i < N / 8; ++i) zr[u][i] = zn[u][i];
    }
}

__global__ __launch_bounds__(256, 1) void mlp_kernel(const f16* __restrict__ ht,
                                                     const float* __restrict__ x,
                                                     MlpP mp,
                                                     float* __restrict__ out) {
    __shared__ f16 wl[64 * 288];  // 36 KiB weight chunk
    __shared__ float bl[64];
    const int tid = threadIdx.x;
    const int tokl = tid >> 2, s = tid & 3;
    const size_t tok0 = (size_t)blockIdx.x * 256 + tokl * 4;

    uint zr[4][36];  // this thread's K-quarter of z, 4 tokens
    uint zn[4][32];

    // build z0 (KR=288): [h(256) | x_fixed(5) | pad]; quarter = 72 f16 = 36 pairs
#pragma unroll
    for (int u = 0; u < 4; ++u) {
        size_t tok = tok0 + u;
        if (s < 3) {
            const uint4* p = (const uint4*)(ht + tok * 256 + s * 72);
#pragma unroll
            for (int q = 0; q < 9; ++q) {
                uint4 w = p[q];
                zr[u][q * 4 + 0] = w.x;
                zr[u][q * 4 + 1] = w.y;
                zr[u][q * 4 + 2] = w.z;
                zr[u][q * 4 + 3] = w.w;
            }
        } else {
            const uint4* p = (const uint4*)(ht + tok * 256 + 216);
#pragma unroll
            for (int q = 0; q < 5; ++q) {
                uint4 w = p[q];
                zr[u][q * 4 + 0] = w.x;
                zr[u][q * 4 + 1] = w.y;
                zr[u][q * 4 + 2] = w.z;
                zr[u][q * 4 + 3] = w.w;
            }
            const float* xp = x + tok * 12 + 7;
            f16 x0 = (f16)xp[0], x1 = (f16)xp[1], x2 = (f16)xp[2], x3 = (f16)xp[3],
                x4 = (f16)xp[4];
            f16 z_ = (f16)0.f;
            f16 pr0[2] = {x0, x1}, pr1[2] = {x2, x3}, pr2[2] = {x4, z_};
            zr[u][20] = *(const uint*)pr0;
            zr[u][21] = *(const uint*)pr1;
            zr[u][22] = *(const uint*)pr2;
#pragma unroll
            for (int q = 23; q < 36; ++q) zr[u][q] = 0;
        }
    }

    mlp_layer<288, 256, false>(mp.w[0], mp.b[0], wl, bl, zr, zn, tid, s, tok0, out);
    mlp_layer<256, 128, false>(mp.w[1], mp.b[1], wl, bl, zr, zn, tid, s, tok0, out);
    mlp_layer<128, 64, false>(mp.w[2], mp.b[2], wl, bl, zr, zn, tid, s, tok0, out);
    mlp_layer<64, 32, false>(mp.w[3], mp.b[3], wl, bl, zr, zn, tid, s, tok0, out);
    mlp_layer<32, 16, false>(mp.w[4], mp.b[4], wl, bl, zr, zn, tid, s, tok0, out);
    mlp_layer<16, 8, false>(mp.w[5], mp.b[5], wl, bl, zr, zn, tid, s, tok0, out);
    mlp_layer<8, 7, true>(mp.w[6], mp.b[6], wl, bl, zr, zn, tid, s, tok0, out);
}

// ============ launch ============
extern "C" void kernel_launch(void* const* d_in, const int* in_sizes, int n_in,
                              void* d_out, int out_size, void* d_ws, size_t ws_size,
                              hipStream_t stream) {
    const float* x = (const float*)d_in[0];
    const float* Wih = (const float*)d_in[1];
    const float* Whh = (const float*)d_in[2];
    const float* bih = (const float*)d_in[3];
    const float* bhh = (const float*)d_in[4];
    const float* W[7];
    const float* bb[7];
    for (int j = 0; j < 7; ++j) {
        W[j] = (const float*)d_in[5 + 2 * j];
        bb[j] = (const float*)d_in[6 + 2 * j];
    }
    float* out = (float*)d_out;

    static const int Kd[7] = {261, 256, 128, 64, 32, 16, 8};
    static const int KRd[7] = {288, 256, 128, 64, 32, 16, 8};
    static const int Nd[7] = {256, 128, 64, 32, 16, 8, 7};

    // workspace layout
    char* ws = (char*)d_ws;
    f16* ht = (f16*)ws;  // 128 MiB
    size_t off = (size_t)NTOK * HH * 2;
    uint4* Wsw = (uint4*)(ws + off);
    off += (size_t)256 * 32 * 16;
    f16* wp[7];
    for (int j = 0; j < 7; ++j) {
        wp[j] = (f16*)(ws + off);
        off += (size_t)Nd[j] * KRd[j] * 2;
        off = (off + 15) & ~(size_t)15;
    }

    rnn_wswz_kernel<<<32, 256, 0, stream>>>(Whh, Wsw);
    for (int j = 0; j < 7; ++j)
        mlp_wpad_kernel<<<(Nd[j] * KRd[j] + 255) / 256, 256, 0, stream>>>(W[j], wp[j], Nd[j],
                                                                          Kd[j], KRd[j]);

    rnn_kernel<<<BB, 256, 0, stream>>>(x, Wsw, Wih, bih, bhh, ht, out + (size_t)NTOK * 7);

    MlpP mp;
    for (int j = 0; j < 7; ++j) {
        mp.w[j] = wp[j];
        mp.b[j] = bb[j];
    }
    mlp_kernel<<<NTOK / 256, 256, 0, stream>>>(ht, x, mp, out);
}

// Round 3
// 3470.808 us; speedup vs baseline: 1.4398x; 1.0091x over previous
//
#include <hip/hip_runtime.h>

#define BB 64
#define TT 4096
#define HH 256
#define NTOK (BB * TT)

typedef _Float16 f16;
typedef _Float16 f16x2 __attribute__((ext_vector_type(2)));
typedef unsigned int uint;
typedef unsigned short ushort;

__device__ __forceinline__ f16x2 u2h(uint u) { return __builtin_bit_cast(f16x2, u); }

__device__ __forceinline__ float fdot2(f16x2 a, f16x2 b, float c) {
    return __builtin_amdgcn_fdot2(a, b, c, false);
}

// DPP quad_perm shuffles (VALU-only): return partner's value
__device__ __forceinline__ float dpp_xor1(float v) {  // quad_perm [1,0,3,2]
    int t = __builtin_amdgcn_update_dpp(0, __builtin_bit_cast(int, v), 0xB1, 0xF, 0xF, true);
    return __builtin_bit_cast(float, t);
}
__device__ __forceinline__ float dpp_xor2(float v) {  // quad_perm [2,3,0,1]
    int t = __builtin_amdgcn_update_dpp(0, __builtin_bit_cast(int, v), 0x4E, 0xF, 0xF, true);
    return __builtin_bit_cast(float, t);
}
__device__ __forceinline__ float swz_xor4(float v) {  // ds_swizzle xor 4
    int t = __builtin_amdgcn_ds_swizzle(__builtin_bit_cast(int, v), 0x101F);
    return __builtin_bit_cast(float, t);
}
__device__ __forceinline__ float swz_xor8(float v) {  // ds_swizzle xor 8
    int t = __builtin_amdgcn_ds_swizzle(__builtin_bit_cast(int, v), 0x201F);
    return __builtin_bit_cast(float, t);
}

// ============ prep: W_hh -> per-thread blocks for 512-thread rnn ============
// Thread tid: s=tid&15 (K-sixteenth, cols [s*16,s*16+16)), j8=tid>>4 (rows j8*8+r).
// Slot q holds row j8*8+((q^s)&7)  -> cndmask-free selective butterfly.
// Per thread 16 uint4: idx = tid*16 + q*2 + hf ; cols s*16+hf*8+e.
__global__ __launch_bounds__(256) void rnn_wswz_kernel(const float* __restrict__ Whh,
                                                       uint4* __restrict__ Wsw) {
    int gid = blockIdx.x * 256 + threadIdx.x;  // 512*16 = 8192 uint4
    if (gid >= 512 * 16) return;
    int tid = gid >> 4, q = (gid >> 1) & 7, hf = gid & 1;
    int s = tid & 15, j8 = tid >> 4;
    int row = j8 * 8 + ((q ^ s) & 7);
    int col = s * 16 + hf * 8;
    const float* src = Whh + row * 256 + col;
    f16 v[8];
#pragma unroll
    for (int e = 0; e < 8; ++e) v[e] = (f16)src[e];
    Wsw[gid] = *(const uint4*)v;
}

// ============ prep: MLP weights -> f16, per-quarter padded layout ============
// Row layout: 4 quarters of QS=KR/4+8 f16 (data KR/4, pad 8) -> RS=KR+32.
__global__ __launch_bounds__(256) void mlp_wpad_kernel(const float* __restrict__ W,
                                                       f16* __restrict__ dst,
                                                       int N, int K, int KR) {
    int QS = KR / 4 + 8, RS = KR + 32;
    int gid = blockIdx.x * 256 + threadIdx.x;
    if (gid >= N * RS) return;
    int n = gid / RS, rem = gid - n * RS;
    int s = rem / QS, i = rem - s * QS;
    int k = s * (KR / 4) + i;
    float v = (i < KR / 4 && k < K) ? W[n * K + k] : 0.0f;
    dst[gid] = (f16)v;
}

// ============ RNN: 64 blocks x 512 threads ============
// 16-way K-split, 8 rows/thread, W in 64 arch VGPRs. h split hbA/hbB (2-way
// bank aliasing only). Reduce: xor4/xor2/xor1 (row-permuted slots, no cndmask)
// then xor8 K-half merge. lgkm-only barrier; ht buffered 16 steps.
__global__ __launch_bounds__(512, 2) void rnn_kernel(const float* __restrict__ x,
                                                     const uint4* __restrict__ Wsw,
                                                     const float* __restrict__ Wih,
                                                     const float* __restrict__ bih,
                                                     const float* __restrict__ bhh,
                                                     f16* __restrict__ ht,
                                                     float* __restrict__ hlast) {
    const int b = blockIdx.x, tid = threadIdx.x;
    const int s = tid & 15, j8 = tid >> 4;
    const int jrow = j8 * 8 + (s & 7);
    __shared__ uint4 hA[2][16];   // h[j], (j&15)<8
    __shared__ uint4 hB[2][16];   // h[j], (j&15)>=8
    __shared__ uint4 xs[2][128];  // x tile double buffer (64 rows x 8 f32)

    uint4 wv[16];
    const uint4* wp = Wsw + tid * 16;
#pragma unroll
    for (int i = 0; i < 16; ++i) wv[i] = wp[i];
#pragma unroll
    for (int i = 0; i < 16; ++i)
        asm volatile("" : "+v"(wv[i].x), "+v"(wv[i].y), "+v"(wv[i].z), "+v"(wv[i].w));

    float wih[7];
#pragma unroll
    for (int i = 0; i < 7; ++i) wih[i] = Wih[jrow * 7 + i];
    const float bias = bih[jrow] + bhh[jrow];

    const float* xb = x + (size_t)b * TT * 12;
    uint4 xpre = make_uint4(0, 0, 0, 0);
    if (tid < 128) {
        int row = tid >> 1, u = tid & 1;
        xs[0][row * 2 + u] = *(const uint4*)(xb + row * 12 + u * 4);
        xpre = *(const uint4*)(xb + (64 + row) * 12 + u * 4);
    }
    if (tid < 16) hA[0][tid] = make_uint4(0, 0, 0, 0);
    else if (tid < 32) hB[0][tid - 16] = make_uint4(0, 0, 0, 0);
    __syncthreads();

    ushort hst[16];
    float hfin = 0.f;
    for (int tb = 0; tb < TT / 16; ++tb) {
#pragma unroll
        for (int k = 0; k < 16; ++k) {
            const int t = tb * 16 + k;
            const int cur = k & 1;
            const int tile = (t >> 6) & 1, tstep = t & 63;

            // x contribution (uniform broadcast)
            const float4 xa = ((const float4*)xs[tile])[tstep * 2];
            const float4 xc = ((const float4*)xs[tile])[tstep * 2 + 1];
            float xw = fmaf(xa.x, wih[0], bias);
            xw = fmaf(xa.y, wih[1], xw);
            xw = fmaf(xa.z, wih[2], xw);
            xw = fmaf(xa.w, wih[3], xw);
            xw = fmaf(xc.x, wih[4], xw);
            xw = fmaf(xc.y, wih[5], xw);
            xw = fmaf(xc.z, wih[6], xw);

            // this thread's 16 h values (cols [s*16, s*16+16))
            uint4 ha = hA[cur][s];
            uint4 hb_ = hB[cur][s];

            float acc[8];
#pragma unroll
            for (int q = 0; q < 8; ++q) {
                float a = 0.f;
                a = fdot2(u2h(ha.x), u2h(wv[q * 2].x), a);
                a = fdot2(u2h(ha.y), u2h(wv[q * 2].y), a);
                a = fdot2(u2h(ha.z), u2h(wv[q * 2].z), a);
                a = fdot2(u2h(ha.w), u2h(wv[q * 2].w), a);
                a = fdot2(u2h(hb_.x), u2h(wv[q * 2 + 1].x), a);
                a = fdot2(u2h(hb_.y), u2h(wv[q * 2 + 1].y), a);
                a = fdot2(u2h(hb_.z), u2h(wv[q * 2 + 1].z), a);
                a = fdot2(u2h(hb_.w), u2h(wv[q * 2 + 1].w), a);
                acc[q] = a;
            }
            // cndmask-free selective butterfly (slots pre-permuted by q^s)
#pragma unroll
            for (int i = 0; i < 4; ++i) acc[i] = acc[i] + swz_xor4(acc[i + 4]);
#pragma unroll
            for (int i = 0; i < 2; ++i) acc[i] = acc[i] + dpp_xor2(acc[i + 2]);
            float acc0 = acc[0] + dpp_xor1(acc[1]);
            float pre = acc0 + swz_xor8(acc0) + xw;  // merge K-halves

            float ax = fabsf(pre);
            float e = __expf(-2.0f * ax);
            float th = __fdividef(1.0f - e, 1.0f + e);
            float h = copysignf(th, pre);

            if (s < 8) {
                f16 hf = (f16)h;
                f16* hout = (f16*)((j8 & 1) ? hB[cur ^ 1] : hA[cur ^ 1]);
                hout[(j8 >> 1) * 8 + s] = hf;
                hst[k] = __builtin_bit_cast(ushort, hf);
                if (t == TT - 1) hfin = h;
            }

            if (tstep == 32 && tid < 128) {
                int row = tid >> 1, u = tid & 1;
                xs[tile ^ 1][row * 2 + u] = xpre;
                int nt = (t & ~63) + 128 + row;
                if (nt > TT - 1) nt = TT - 1;
                xpre = *(const uint4*)(xb + nt * 12 + u * 4);
            }
            asm volatile("s_waitcnt lgkmcnt(0)\n\ts_barrier" ::: "memory");
        }
        if (s < 8) {
            size_t base = (size_t)b * TT * HH + (size_t)(tb * 16) * HH + jrow;
#pragma unroll
            for (int k = 0; k < 16; ++k)
                ht[base + (size_t)k * HH] = __builtin_bit_cast(f16, hst[k]);
        }
    }
    if (s < 8) hlast[b * HH + jrow] = hfin;
}

// ============ MLP: 4096 blocks x 256 threads, 64 tokens/block ============
// quad lane s owns K-quarter s (regs, constant-indexed) and output quarter s
// (== next layer's K-quarter). New activations bounce through LDS zbuf
// (dynamic LDS ok; no register dynamic indexing -> no scratch).
struct MlpP {
    const f16* w[7];
    const float* b[7];
};

#define ZQS 72   // zbuf quarter stride (f16), 144B: b128-aligned
#define ZTS 288  // zbuf token stride

template <int KR>
__device__ __forceinline__ void load_z(const f16* zbuf, uint* zr, int tokl, int s) {
    const f16* src = zbuf + tokl * ZTS + s * ZQS;
    if constexpr (KR >= 32) {
        const uint4* p = (const uint4*)src;
#pragma unroll
        for (int i = 0; i < KR / 32; ++i) {
            uint4 v = p[i];
            zr[i * 4 + 0] = v.x;
            zr[i * 4 + 1] = v.y;
            zr[i * 4 + 2] = v.z;
            zr[i * 4 + 3] = v.w;
        }
    } else if constexpr (KR == 16) {
        uint2 v = *(const uint2*)src;
        zr[0] = v.x;
        zr[1] = v.y;
    } else {
        zr[0] = *(const uint*)src;
    }
}

template <int KR, int N, bool LAST>
__device__ __forceinline__ void mlp_layer(const f16* __restrict__ wg,
                                          const float* __restrict__ bg,
                                          f16* wl, f16* zbuf, float* bl,
                                          const uint* zr, int tid, int s,
                                          int tokl, size_t tok,
                                          float* __restrict__ out) {
    constexpr int QS = KR / 4 + 8;
    constexpr int RS = KR + 32;
    constexpr int P = KR / 8;
    constexpr int CN = (N < 16) ? N : 16;
    constexpr int NQ = N / 4;
    const uint4* wg4 = (const uint4*)wg;
    for (int n0 = 0; n0 < N; n0 += CN) {
        const int cnt = CN * RS / 8;
        const int base4 = n0 * (RS / 8);
        for (int idx = tid; idx < cnt; idx += 256)
            ((uint4*)wl)[idx] = wg4[base4 + idx];
        if (tid < CN) bl[tid] = bg[n0 + tid];
        __syncthreads();

        for (int nn = 0; nn < CN; ++nn) {
            const f16* wrow = wl + nn * RS + s * QS;
            float a = 0.f;
            if constexpr (P >= 4) {
                const uint4* w4 = (const uint4*)wrow;
#pragma unroll
                for (int i = 0; i < P / 4; ++i) {
                    uint4 wb = w4[i];
                    a = fdot2(u2h(zr[i * 4 + 0]), u2h(wb.x), a);
                    a = fdot2(u2h(zr[i * 4 + 1]), u2h(wb.y), a);
                    a = fdot2(u2h(zr[i * 4 + 2]), u2h(wb.z), a);
                    a = fdot2(u2h(zr[i * 4 + 3]), u2h(wb.w), a);
                }
            } else if constexpr (P == 2) {
                uint2 wb = *(const uint2*)wrow;
                a = fdot2(u2h(zr[0]), u2h(wb.x), a);
                a = fdot2(u2h(zr[1]), u2h(wb.y), a);
            } else {
                a = fdot2(u2h(zr[0]), u2h(*(const uint*)wrow), a);
            }
            float v = a;
            v += dpp_xor1(v);
            v += dpp_xor2(v);  // full quad sum on all 4 lanes
            v += bl[nn];
            const int n = n0 + nn;
            if constexpr (LAST) {
                if ((n >> 1) == s) out[tok * 7 + n] = v;
            } else {
                v = (v > 0.f) ? v : 0.01f * v;
                if (n / NQ == s)
                    zbuf[tokl * ZTS + s * ZQS + (n - s * NQ)] = (f16)v;
            }
        }
        __syncthreads();
    }
}

__global__ __launch_bounds__(256, 3) void mlp_kernel(const f16* __restrict__ ht,
                                                     const float* __restrict__ x,
                                                     MlpP mp,
                                                     float* __restrict__ out) {
    __shared__ f16 zbuf[64 * ZTS];   // 36864 B
    __shared__ f16 wl[16 * 320];     // 10240 B
    __shared__ float bl[16];
    const int tid = threadIdx.x;
    const int s = tid & 3, tokl = tid >> 2;
    const size_t tok = (size_t)blockIdx.x * 64 + tokl;

    uint zr[36];  // this lane's K-quarter (max 72 f16 for K=288)

    // z0 = [h(256) | x_fixed(5) | pad] ; quarter = 72 f16
    if (s < 3) {
        const uint4* p = (const uint4*)(ht + tok * 256 + s * 72);
#pragma unroll
        for (int q = 0; q < 9; ++q) {
            uint4 w = p[q];
            zr[q * 4 + 0] = w.x;
            zr[q * 4 + 1] = w.y;
            zr[q * 4 + 2] = w.z;
            zr[q * 4 + 3] = w.w;
        }
    } else {
        const uint4* p = (const uint4*)(ht + tok * 256 + 216);
#pragma unroll
        for (int q = 0; q < 5; ++q) {
            uint4 w = p[q];
            zr[q * 4 + 0] = w.x;
            zr[q * 4 + 1] = w.y;
            zr[q * 4 + 2] = w.z;
            zr[q * 4 + 3] = w.w;
        }
        const float* xp = x + tok * 12 + 7;
        f16 pr0[2] = {(f16)xp[0], (f16)xp[1]};
        f16 pr1[2] = {(f16)xp[2], (f16)xp[3]};
        f16 pr2[2] = {(f16)xp[4], (f16)0.f};
        zr[20] = *(const uint*)pr0;
        zr[21] = *(const uint*)pr1;
        zr[22] = *(const uint*)pr2;
#pragma unroll
        for (int q = 23; q < 36; ++q) zr[q] = 0;
    }

    mlp_layer<288, 256, false>(mp.w[0], mp.b[0], wl, zbuf, bl, zr, tid, s, tokl, tok, out);
    load_z<256>(zbuf, zr, tokl, s);
    mlp_layer<256, 128, false>(mp.w[1], mp.b[1], wl, zbuf, bl, zr, tid, s, tokl, tok, out);
    load_z<128>(zbuf, zr, tokl, s);
    mlp_layer<128, 64, false>(mp.w[2], mp.b[2], wl, zbuf, bl, zr, tid, s, tokl, tok, out);
    load_z<64>(zbuf, zr, tokl, s);
    mlp_layer<64, 32, false>(mp.w[3], mp.b[3], wl, zbuf, bl, zr, tid, s, tokl, tok, out);
    load_z<32>(zbuf, zr, tokl, s);
    mlp_layer<32, 16, false>(mp.w[4], mp.b[4], wl, zbuf, bl, zr, tid, s, tokl, tok, out);
    load_z<16>(zbuf, zr, tokl, s);
    mlp_layer<16, 8, false>(mp.w[5], mp.b[5], wl, zbuf, bl, zr, tid, s, tokl, tok, out);
    load_z<8>(zbuf, zr, tokl, s);
    mlp_layer<8, 7, true>(mp.w[6], mp.b[6], wl, zbuf, bl, zr, tid, s, tokl, tok, out);
}

// ============ launch ============
extern "C" void kernel_launch(void* const* d_in, const int* in_sizes, int n_in,
                              void* d_out, int out_size, void* d_ws, size_t ws_size,
                              hipStream_t stream) {
    const float* x = (const float*)d_in[0];
    const float* Wih = (const float*)d_in[1];
    const float* Whh = (const float*)d_in[2];
    const float* bih = (const float*)d_in[3];
    const float* bhh = (const float*)d_in[4];
    const float* W[7];
    const float* bb[7];
    for (int j = 0; j < 7; ++j) {
        W[j] = (const float*)d_in[5 + 2 * j];
        bb[j] = (const float*)d_in[6 + 2 * j];
    }
    float* out = (float*)d_out;

    static const int Kd[7] = {261, 256, 128, 64, 32, 16, 8};
    static const int KRd[7] = {288, 256, 128, 64, 32, 16, 8};
    static const int Nd[7] = {256, 128, 64, 32, 16, 8, 7};

    char* ws = (char*)d_ws;
    f16* ht = (f16*)ws;  // 128 MiB
    size_t off = (size_t)NTOK * HH * 2;
    uint4* Wsw = (uint4*)(ws + off);
    off += (size_t)512 * 16 * 16;
    f16* wp[7];
    for (int j = 0; j < 7; ++j) {
        wp[j] = (f16*)(ws + off);
        off += (size_t)Nd[j] * (KRd[j] + 32) * 2;
        off = (off + 15) & ~(size_t)15;
    }

    rnn_wswz_kernel<<<32, 256, 0, stream>>>(Whh, Wsw);
    for (int j = 0; j < 7; ++j) {
        int n = Nd[j] * (KRd[j] + 32);
        mlp_wpad_kernel<<<(n + 255) / 256, 256, 0, stream>>>(W[j], wp[j], Nd[j], Kd[j], KRd[j]);
    }

    rnn_kernel<<<BB, 512, 0, stream>>>(x, Wsw, Wih, bih, bhh, ht, out + (size_t)NTOK * 7);

    MlpP mp;
    for (int j = 0; j < 7; ++j) {
        mp.w[j] = wp[j];
        mp.b[j] = bb[j];
    }
    mlp_kernel<<<NTOK / 64, 256, 0, stream>>>(ht, x, mp, out);
}

// Round 5
// 2862.082 us; speedup vs baseline: 1.7460x; 1.2127x over previous
//
#include <hip/hip_runtime.h>

#define BB 64
#define TT 4096
#define HH 256
#define NTOK (BB * TT)

typedef _Float16 f16;
typedef _Float16 f16x2 __attribute__((ext_vector_type(2)));
typedef unsigned int uint;
typedef unsigned short ushort;
typedef uint uint4v __attribute__((ext_vector_type(4)));

__device__ __forceinline__ f16x2 u2h(uint u) { return __builtin_bit_cast(f16x2, u); }

__device__ __forceinline__ float fdot2(f16x2 a, f16x2 b, float c) {
    return __builtin_amdgcn_fdot2(a, b, c, false);
}

__device__ __forceinline__ uint pk_rtz(float a, float b) {  // v_cvt_pkrtz_f16_f32 -> uint
    auto p = __builtin_amdgcn_cvt_pkrtz(a, b);
    return __builtin_bit_cast(uint, p);
}

__device__ __forceinline__ float dpp_xor1(float v) {  // quad_perm [1,0,3,2]
    int t = __builtin_amdgcn_update_dpp(0, __builtin_bit_cast(int, v), 0xB1, 0xF, 0xF, true);
    return __builtin_bit_cast(float, t);
}
__device__ __forceinline__ float dpp_xor2(float v) {  // quad_perm [2,3,0,1]
    int t = __builtin_amdgcn_update_dpp(0, __builtin_bit_cast(int, v), 0x4E, 0xF, 0xF, true);
    return __builtin_bit_cast(float, t);
}

__device__ __forceinline__ uint packf16(float a, float b) {  // RNE pack (prep only)
    ushort lo = __builtin_bit_cast(ushort, (f16)a);
    ushort hi = __builtin_bit_cast(ushort, (f16)b);
    return (uint)lo | ((uint)hi << 16);
}

// ============ prep: W_hh -> per-thread register blocks ============
// RNN thread tid: qd=tid>>2, s=tid&3 (K-quarter, cols [64s,64s+64)).
// Slot q (q<4) holds row 4qd + (q^s); uint i (i<32) = cols 64s+2i, 64s+2i+1.
__global__ __launch_bounds__(256) void rnn_wswz_kernel(const float* __restrict__ Whh,
                                                       uint* __restrict__ Wsw) {
    int gid = blockIdx.x * 256 + threadIdx.x;  // 256*128 uints
    if (gid >= 256 * 128) return;
    int tid = gid >> 7, rem = gid & 127;
    int q = rem >> 5, i = rem & 31;
    int qd = tid >> 2, s = tid & 3;
    int row = 4 * qd + (q ^ s);
    int col = 64 * s + 2 * i;
    Wsw[gid] = packf16(Whh[row * 256 + col], Whh[row * 256 + col + 1]);
}

// ============ prep: MLP weights, pair-interleaved + bias-in-K ============
// Lane s owns k ≡ s (mod 4). Quarter = UQ uints: j<PJ: pair (k=8j+s, 8j+4+s);
// j==PJ: (bias, 0); j>PJ: 0.  Row = 4 quarters of UQ uints.
__global__ __launch_bounds__(256) void mlp_wpad_kernel(const float* __restrict__ W,
                                                       const float* __restrict__ bsrc,
                                                       uint* __restrict__ dst,
                                                       int N, int Kreal, int PJ, int UQ) {
    int gid = blockIdx.x * 256 + threadIdx.x;
    if (gid >= N * 4 * UQ) return;
    int n = gid / (4 * UQ);
    int rem = gid - n * 4 * UQ;
    int s = rem / UQ;
    int j = rem - s * UQ;
    uint val = 0;
    if (j < PJ) {
        int k0 = 8 * j + s, k1 = 8 * j + 4 + s;
        float f0 = (k0 < Kreal) ? W[n * Kreal + k0] : 0.f;
        float f1 = (k1 < Kreal) ? W[n * Kreal + k1] : 0.f;
        val = packf16(f0, f1);
    } else if (j == PJ) {
        val = packf16(bsrc[n], 0.f);
    }
    dst[gid] = val;
}

// ============ RNN: 64 blocks x 256 threads ============
// 4-way K-split (quads), 4 rows/thread, W in 128 pinned VGPRs.
// Reduce: 3 DPP adds only. h LDS quarters padded (144B stride, conflict-free).
// ht stored PERMUTED: position 64s+a holds h[4a+s] (pair layout for MLP).
__global__ __launch_bounds__(256, 1) void rnn_kernel(const float* __restrict__ x,
                                                     const uint* __restrict__ Wsw,
                                                     const float* __restrict__ Wih,
                                                     const float* __restrict__ bih,
                                                     const float* __restrict__ bhh,
                                                     f16* __restrict__ ht,
                                                     float* __restrict__ hlast) {
    const int b = blockIdx.x, tid = threadIdx.x;
    const int s = tid & 3;
    __shared__ __align__(16) char hbuf[2][576];  // 4 quarters x 144B each
    __shared__ uint4 xs[2][128];                 // 64 rows x 32B, double-buffered

    uint4v wv[32];  // slot q = wv[q*8 .. q*8+7]
    {
        const uint4v* wp = (const uint4v*)(Wsw + (size_t)tid * 128);
#pragma unroll
        for (int i = 0; i < 32; ++i) wv[i] = wp[i];
    }
#pragma unroll
    for (int i = 0; i < 32; ++i) asm volatile("" : "+v"(wv[i]));

    float wih[7];
#pragma unroll
    for (int i = 0; i < 7; ++i) wih[i] = Wih[tid * 7 + i];
    const float bias = bih[tid] + bhh[tid];

    const float* xb = x + (size_t)b * TT * 12;
    uint4 xpre = make_uint4(0, 0, 0, 0);
    if (tid < 128) {
        int row = tid >> 1, u = tid & 1;
        xs[0][row * 2 + u] = *(const uint4*)(xb + row * 12 + u * 4);
        xpre = *(const uint4*)(xb + (64 + row) * 12 + u * 4);
    }
    if (tid < 144) ((uint*)hbuf[0])[tid] = 0;  // zero h0 (incl. pads)
    __syncthreads();

    f16* htp = ht + (size_t)b * TT * 256 + (size_t)(s * 64 + (tid >> 2));
    ushort hst[16];

    for (int tb = 0; tb < 256; ++tb) {
#pragma unroll
        for (int k = 0; k < 16; ++k) {
            const int t = tb * 16 + k;
            const int cur = k & 1;
            const int tile = (t >> 6) & 1, tstep = t & 63;

            // x contribution (wave-uniform broadcast reads)
            const float4 xa = ((const float4*)xs[tile])[tstep * 2];
            const float4 xc = ((const float4*)xs[tile])[tstep * 2 + 1];
            float xw = fmaf(xa.x, wih[0], bias);
            xw = fmaf(xa.y, wih[1], xw);
            xw = fmaf(xa.z, wih[2], xw);
            xw = fmaf(xa.w, wih[3], xw);
            xw = fmaf(xc.x, wih[4], xw);
            xw = fmaf(xc.y, wih[5], xw);
            xw = fmaf(xc.z, wih[6], xw);

            // this lane's K-quarter of h (64 f16), padded conflict-free layout
            const uint4* hq = (const uint4*)(hbuf[cur] + s * 144);
            uint hhv[32];
#pragma unroll
            for (int i = 0; i < 8; ++i) {
                uint4 v = hq[i];
                hhv[4 * i + 0] = v.x;
                hhv[4 * i + 1] = v.y;
                hhv[4 * i + 2] = v.z;
                hhv[4 * i + 3] = v.w;
            }

            float acc[4] = {0.f, 0.f, 0.f, 0.f};
#pragma unroll
            for (int q = 0; q < 4; ++q)
#pragma unroll
                for (int i = 0; i < 8; ++i) {
                    uint4v w = wv[q * 8 + i];
                    acc[q] = fdot2(u2h(hhv[4 * i + 0]), u2h(w.x), acc[q]);
                    acc[q] = fdot2(u2h(hhv[4 * i + 1]), u2h(w.y), acc[q]);
                    acc[q] = fdot2(u2h(hhv[4 * i + 2]), u2h(w.z), acc[q]);
                    acc[q] = fdot2(u2h(hhv[4 * i + 3]), u2h(w.w), acc[q]);
                }

            // slot-permuted butterfly: lane s ends with row 4qd+s == tid
            float uu = acc[0] + dpp_xor1(acc[1]);
            float vv = acc[2] + dpp_xor1(acc[3]);
            float pre = uu + dpp_xor2(vv) + xw;

            // tanh(x) = 2/(1+e^-2x) - 1
            float e = __expf(-2.0f * pre);
            float r = __builtin_amdgcn_rcpf(1.0f + e);
            float h = fmaf(2.0f, r, -1.0f);

            f16 hf = (f16)h;
            *(f16*)(hbuf[cur ^ 1] + (tid >> 6) * 144 + (tid & 63) * 2) = hf;
            hst[k] = __builtin_bit_cast(ushort, hf);
            if (k == 15 && tb == 255) hlast[b * 256 + tid] = h;

            if (tstep == 32 && tid < 128) {
                int row = tid >> 1, u = tid & 1;
                xs[tile ^ 1][row * 2 + u] = xpre;
                int nt = (t & ~63) + 128 + row;
                if (nt > TT - 1) nt = TT - 1;
                xpre = *(const uint4*)(xb + nt * 12 + u * 4);
            }
            asm volatile("s_waitcnt lgkmcnt(0)\n\ts_barrier" ::: "memory");
        }
        const size_t base = (size_t)(tb * 16) * 256;
#pragma unroll
        for (int k = 0; k < 16; ++k)
            htp[base + (size_t)k * 256] = __builtin_bit_cast(f16, hst[k]);
    }
}

// ============ MLP: 4096 blocks x 256 threads, 64 tokens/block ============
// Lane s owns k ≡ s mod 4 (z in regs). Weights LDS-staged in chunks; outputs
// selected by cndmask tree, bounced through padded LDS zbuf (dynamic index).
struct MlpP {
    const uint* w0;
    const uint* w1;
    const uint* w2;
    const uint* wt;  // L3..L6 contiguous
};

template <int UQ, int N>
__device__ __forceinline__ void layer_comp(const uint* __restrict__ wb, const uint z[36],
                                           uint* zbuf, int zoff, int tid, int s,
                                           bool s1, bool s2) {
    for (int n8 = 0; n8 < N / 8; ++n8) {
        float v[8];
#pragma unroll
        for (int u = 0; u < 8; ++u) {
            const uint4* wr = (const uint4*)(wb + ((n8 * 8 + u) * 4 + s) * UQ);
            float a = 0.f;
#pragma unroll
            for (int j = 0; j < UQ / 4; ++j) {
                uint4 wq = wr[j];
                a = fdot2(u2h(z[4 * j + 0]), u2h(wq.x), a);
                a = fdot2(u2h(z[4 * j + 1]), u2h(wq.y), a);
                a = fdot2(u2h(z[4 * j + 2]), u2h(wq.z), a);
                a = fdot2(u2h(z[4 * j + 3]), u2h(wq.w), a);
            }
            a += dpp_xor1(a);
            a += dpp_xor2(a);            // full quad sum on all lanes
            v[u] = fmaxf(a, 0.01f * a);  // leaky relu
        }
        float lo = s2 ? (s1 ? v[3] : v[2]) : (s1 ? v[1] : v[0]);  // v[s]
        float hi = s2 ? (s1 ? v[7] : v[6]) : (s1 ? v[5] : v[4]);  // v[s+4]
        zbuf[tid * 33 + zoff + n8] = pk_rtz(lo, hi);
    }
}

template <int UQ, int N, int CN>
__device__ __forceinline__ void layer_big(const uint* __restrict__ wg, uint* wl, uint* zbuf,
                                          const uint z[36], int tid, int s, bool s1, bool s2) {
    for (int c = 0; c < N / CN; ++c) {
        __syncthreads();
        const uint4* src = (const uint4*)wg + (size_t)c * (CN * UQ);
        uint4* dstv = (uint4*)wl;
        for (int idx = tid; idx < CN * UQ; idx += 256) dstv[idx] = src[idx];
        __syncthreads();
        layer_comp<UQ, CN>(wl, z, zbuf, c * (CN / 8), tid, s, s1, s2);
    }
}

__global__ __launch_bounds__(256, 3) void mlp_kernel(const f16* __restrict__ ht,
                                                     const float* __restrict__ x,
                                                     MlpP mp, float* __restrict__ out) {
    __shared__ uint zbuf[256 * 33];  // 33792 B, stride-33 conflict-free
    __shared__ uint wl[4608];        // 18432 B weight chunk
    const int tid = threadIdx.x;
    const int s = tid & 3;
    const bool s1 = (s & 1) != 0, s2 = (s & 2) != 0;
    const size_t tok = (size_t)blockIdx.x * 64 + (tid >> 2);
    const uint bz = (s == 0) ? 0x00003C00u : 0u;  // f16 1.0 on lane 0

    uint z[36];
    {
        const uint4* hp = (const uint4*)(ht + tok * 256 + s * 64);
#pragma unroll
        for (int i = 0; i < 8; ++i) {
            uint4 v = hp[i];
            z[4 * i + 0] = v.x;
            z[4 * i + 1] = v.y;
            z[4 * i + 2] = v.z;
            z[4 * i + 3] = v.w;
        }
        const float* xp = x + tok * 12 + 7;
        float x0 = xp[s];
        float x1 = (s == 0) ? xp[4] : 0.f;
        z[32] = pk_rtz(x0, x1);
        z[33] = bz;
        z[34] = 0;
        z[35] = 0;
    }

    layer_big<36, 256, 32>(mp.w0, wl, zbuf, z, tid, s, s1, s2);
#pragma unroll
    for (int i = 0; i < 32; ++i) z[i] = zbuf[tid * 33 + i];
    z[32] = bz; z[33] = 0; z[34] = 0; z[35] = 0;

    layer_big<36, 128, 32>(mp.w1, wl, zbuf, z, tid, s, s1, s2);
#pragma unroll
    for (int i = 0; i < 16; ++i) z[i] = zbuf[tid * 33 + i];
    z[16] = bz; z[17] = 0; z[18] = 0; z[19] = 0;

    layer_big<20, 64, 32>(mp.w2, wl, zbuf, z, tid, s, s1, s2);
#pragma unroll
    for (int i = 0; i < 8; ++i) z[i] = zbuf[tid * 33 + i];
    z[8] = bz; z[9] = 0; z[10] = 0; z[11] = 0;

    // stage L3..L6 (2288 uints contiguous)
    __syncthreads();
    {
        const uint4* src = (const uint4*)mp.wt;
        uint4* dstv = (uint4*)wl;
        for (int idx = tid; idx < 572; idx += 256) dstv[idx] = src[idx];
    }
    __syncthreads();

    layer_comp<12, 32>(wl + 0, z, zbuf, 0, tid, s, s1, s2);
#pragma unroll
    for (int i = 0; i < 4; ++i) z[i] = zbuf[tid * 33 + i];
    z[4] = bz; z[5] = 0; z[6] = 0; z[7] = 0;

    layer_comp<8, 16>(wl + 1536, z, zbuf, 0, tid, s, s1, s2);
    z[0] = zbuf[tid * 33 + 0];
    z[1] = zbuf[tid * 33 + 1];
    z[2] = bz;
    z[3] = 0;

    layer_comp<4, 8>(wl + 2048, z, zbuf, 0, tid, s, s1, s2);
    z[0] = zbuf[tid * 33 + 0];
    z[1] = bz;
    z[2] = 0;
    z[3] = 0;

    // L7 head (N=7), bias in K, no activation
    {
        const uint* wb = wl + 2176;
#pragma unroll
        for (int n = 0; n < 7; ++n) {
            const uint4 wq = *(const uint4*)(wb + (n * 4 + s) * 4);
            float a = 0.f;
            a = fdot2(u2h(z[0]), u2h(wq.x), a);
            a = fdot2(u2h(z[1]), u2h(wq.y), a);
            a = fdot2(u2h(z[2]), u2h(wq.z), a);
            a = fdot2(u2h(z[3]), u2h(wq.w), a);
            a += dpp_xor1(a);
            a += dpp_xor2(a);
            if ((n & 3) == s) out[tok * 7 + n] = a;
        }
    }
}

// ============ launch ============
extern "C" void kernel_launch(void* const* d_in, const int* in_sizes, int n_in,
                              void* d_out, int out_size, void* d_ws, size_t ws_size,
                              hipStream_t stream) {
    const float* x = (const float*)d_in[0];
    const float* Wih = (const float*)d_in[1];
    const float* Whh = (const float*)d_in[2];
    const float* bih = (const float*)d_in[3];
    const float* bhh = (const float*)d_in[4];
    const float* W[7];
    const float* bb[7];
    for (int j = 0; j < 7; ++j) {
        W[j] = (const float*)d_in[5 + 2 * j];
        bb[j] = (const float*)d_in[6 + 2 * j];
    }
    float* out = (float*)d_out;

    static const int Kd[7] = {261, 256, 128, 64, 32, 16, 8};
    static const int Nd[7] = {256, 128, 64, 32, 16, 8, 7};
    static const int PJd[7] = {33, 32, 16, 8, 4, 2, 1};
    static const int UQd[7] = {36, 36, 20, 12, 8, 4, 4};

    char* ws = (char*)d_ws;
    f16* ht = (f16*)ws;  // 128 MiB (permuted layout)
    size_t off = (size_t)NTOK * HH * 2;
    uint* Wsw = (uint*)(ws + off);
    off += (size_t)256 * 128 * 4;
    uint* wp[7];
    static const size_t tail_off[4] = {0, 1536, 2048, 2176};  // uints within wt
    uint* wt = nullptr;
    for (int j = 0; j < 7; ++j) {
        if (j < 3) {
            wp[j] = (uint*)(ws + off);
            off += (size_t)Nd[j] * 4 * UQd[j] * 4;
        } else {
            if (j == 3) { wt = (uint*)(ws + off); off += 2288 * 4; }
            wp[j] = wt + tail_off[j - 3];
        }
    }

    rnn_wswz_kernel<<<128, 256, 0, stream>>>(Whh, Wsw);
    for (int j = 0; j < 7; ++j) {
        int tot = Nd[j] * 4 * UQd[j];
        mlp_wpad_kernel<<<(tot + 255) / 256, 256, 0, stream>>>(W[j], bb[j], wp[j], Nd[j], Kd[j],
                                                               PJd[j], UQd[j]);
    }

    rnn_kernel<<<BB, 256, 0, stream>>>(x, Wsw, Wih, bih, bhh, ht, out + (size_t)NTOK * 7);

    MlpP mp;
    mp.w0 = wp[0];
    mp.w1 = wp[1];
    mp.w2 = wp[2];
    mp.wt = wt;
    mlp_kernel<<<NTOK / 64, 256, 0, stream>>>(ht, x, mp, out);
}